// Round 16
// baseline (170.340 us; speedup 1.0000x reference)
//
#include <hip/hip_runtime.h>
#include <hip/hip_bf16.h>

typedef unsigned short u16;
typedef unsigned int   u32;

using bf16x8 = __attribute__((ext_vector_type(8))) short;
using f32x4  = __attribute__((ext_vector_type(4))) float;

// ---------- constants ----------
#define NB    32      // batch
#define CC    64      // in channels
#define WW_   4096    // input width
#define FF    128     // out channels
#define TAPS  9
#define KBINS 3597    // half_compressed
#define N2    7194    // compress_fft_size
#define OW    4088    // out width
#define SIG2  4096    // N*F
#define JMAX  4104    // conv support: tau in [-8,4095], j = tau+8
#define KD    4160    // padded conv length (mult of 64)
#define XTROWS 4352   // 64 zero + 4096 data + 192 zero
#define PBIG  58933248   // 8192*7194 (< 2^31; 2*PBIG also < 2^31)

__device__ __forceinline__ u16 f2bf(float f) {
    u32 u = __float_as_uint(f);
    return (u16)((u + 0x7FFFu + ((u >> 16) & 1u)) >> 16);
}
// HW trig, input in REVOLUTIONS (ISA: D=sin(S0*2pi)), arg kept in [0,1)
__device__ __forceinline__ float vsin(float x) {
    float r; asm("v_sin_f32 %0, %1" : "=v"(r) : "v"(x)); return r;
}
__device__ __forceinline__ float vrcp(float x) {
    float r; asm("v_rcp_f32 %0, %1" : "=v"(r) : "v"(x)); return r;
}

// async global->LDS, 16B per lane; lds dest is wave-uniform base + lane*16
__device__ __forceinline__ void gload16(const void* g, void* l) {
    __builtin_amdgcn_global_load_lds(
        (const __attribute__((address_space(1))) void*)g,
        (__attribute__((address_space(3))) void*)l, 16, 0, 0);
}

// ---------- prep_all: cast_xt (blocks 0..2175) | gen_D (2176..6271) |
//                      F2 (6272..6559) — independent outputs, one launch ----
__global__ __launch_bounds__(256) void prep_all(const float* __restrict__ x,
                                                u16* __restrict__ XT,
                                                u16* __restrict__ D,
                                                const float* __restrict__ filt,
                                                u16* __restrict__ F2) {
    __shared__ u32 tl[64][33];          // cast branch only; [c][i2], +1 pad
    const int tid = threadIdx.x;
    const int b = blockIdx.x;

    if (b < 2176) {                     // ---- cast + transpose x -> XT ----
        const int it = b >> 5, n = b & 31;
        if (it >= 64) {                 // zero rows: R in [0,64) U [4160,4352)
            int zb = it - 64;           // 0..3
            int i2 = tid >> 3, cb = tid & 7;
            bf16x8 z;
#pragma unroll
            for (int q = 0; q < 8; q++) z[q] = 0;
#pragma unroll
            for (int e = 0; e < 2; e++) {
                int zr = zb * 64 + 2 * i2 + e;
                int R = (zr < 64) ? zr : (4096 + zr);
                *(bf16x8*)(XT + ((size_t)n * XTROWS + R) * 64 + cb * 8) = z;
            }
            return;
        }
        const int i0 = it * 64;
        {   // write side: c = tid>>2, 16 consecutive i packed 2/word
            int c = tid >> 2, iq = tid & 3;
            const float4* src = (const float4*)(x + ((size_t)n * CC + c) * WW_ +
                                                i0 + iq * 16);
#pragma unroll
            for (int q = 0; q < 4; q++) {
                float4 v = src[q];
                tl[c][iq * 8 + q * 2]     = (u32)f2bf(v.x) |
                                            ((u32)f2bf(v.y) << 16);
                tl[c][iq * 8 + q * 2 + 1] = (u32)f2bf(v.z) |
                                            ((u32)f2bf(v.w) << 16);
            }
        }
        __syncthreads();
        {   // read side: one u32 per channel gives BOTH rows of the i-pair
            int i2 = tid >> 3, cb = tid & 7;
            int R0 = i0 + 64 + 2 * i2, R1 = R0 + 1;
            bf16x8 vlo, vhi;
#pragma unroll
            for (int ci = 0; ci < 8; ci++) {
                u32 w = tl[cb * 8 + ci][i2];
                vlo[ci] = (short)(u16)(w & 0xffffu);
                vhi[ci] = (short)(u16)(w >> 16);
            }
            *(bf16x8*)(XT + ((size_t)n * XTROWS + R0) * 64 +
                       ((cb ^ (R0 & 7)) * 8)) = vlo;
            *(bf16x8*)(XT + ((size_t)n * XTROWS + R1) * 64 +
                       ((cb ^ (R1 & 7)) * 8)) = vhi;
        }
        return;
    }

    if (b < 2176 + SIG2) {              // ---- Dirichlet table D[t][j] ----
        // D = sin(7193*pi*a)/(N2*sin(pi*a)), a = (8192t - 7194(j-8))/P.
        // Division-free int32: |v| < P -> r = v(+P); 7193r mod 2P =
        // 7194*(r&16383) - r (+2P if <0), since 2P = 7194*16384.
        const int t = b - 2176;
        const int base = 8192 * t;
        u32* row = (u32*)(D + (size_t)t * KD);
        for (int p = tid; p < KD / 2; p += 256) {
            u32 pack = 0;
#pragma unroll
            for (int e = 0; e < 2; e++) {
                int j = 2 * p + e;
                float d = 0.f;
                if (j < JMAX) {
                    int v = base - 7194 * (j - 8);
                    int r = (v < 0) ? v + PBIG : v;
                    if (r == 0) {
                        d = 7193.0f / 7194.0f;
                    } else {
                        int m = 7194 * (r & 16383) - r;   // 7193r mod 2P
                        if (m < 0) m += 2 * PBIG;
                        float num = vsin((float)m *
                                         (float)(0.5 / (double)PBIG));
                        int rr = (r < PBIG - r) ? r : PBIG - r;
                        float den = (rr < (1 << 18))
                            ? (float)rr *
                              (float)(3.14159265358979323846 / (double)PBIG)
                            : vsin((float)r * (float)(0.5 / (double)PBIG));
                        d = num * vrcp(den) * (1.0f / 7194.0f);
                    }
                }
                pack |= (u32)f2bf(d) << (16 * e);
            }
            row[p] = pack;
        }
        return;
    }

    {                                   // ---- F2[f][w*64+c] ----
        int idx = (b - 2176 - SIG2) * 256 + tid;
        if (idx < FF * 576) {
            int f = idx / 576, wc = idx % 576;
            int w = wc >> 6, c = wc & 63;
            F2[idx] = f2bf(filt[((size_t)f * CC + c) * TAPS + w]);
        }
    }
}

// ============ conv9 (r13 v1, known-good): z[n*128+f][j] ====================
// A = F2 (128x576, dbuf per tap); B read DIRECT from staged x window
// (shift = tap), no Z materialization. Block (jt, n), 256 thr, 4 waves.
#define STAGE_A9(T, BUF)                                                    \
    _Pragma("unroll")                                                       \
    for (int q = 0; q < 4; q++) {                                           \
        gload16(F2 + (size_t)(wid * 32 + q * 8 + (lane >> 3)) * 576 +       \
                    (T) * 64 + (((lane & 7) ^ (lane >> 3)) * 8),            \
                lac + (BUF)*16384 + (wid * 32 + q * 8) * 128);              \
    }

__global__ __launch_bounds__(256, 2) void conv9(const u16* __restrict__ XT,
                                                const u16* __restrict__ F2,
                                                u16* __restrict__ Z) {
    __shared__ u16 la[2 * 128 * 64];   // 32 KB A dbuf
    __shared__ u16 lx[96 * 64];        // 12 KB x window (rows l, swz c-blk)
    const int tid = threadIdx.x;
    const int lane = tid & 63, wid = tid >> 6;
    const int jt = blockIdx.x, n = blockIdx.y;
    const int fr = lane & 15;
    const int hk = (lane >> 4) << 4;
    const int askew = (fr & 7) << 4;
    char* lac = (char*)la;
    char* lxc = (char*)lx;

    // stage x window: XT[n] rows jt*64+56 .. +151 (96 rows x 128B), linear.
    {
        const u16* src = XT + ((size_t)n * XTROWS + jt * 64 + 56) * 64;
#pragma unroll
        for (int q = 0; q < 3; q++) {
            int off = (wid * 3 + q) * 512;   // u16 units
            gload16(src + off + lane * 8, lxc + off * 2);
        }
    }
    STAGE_A9(0, 0)
    __syncthreads();

    f32x4 acc[2][4];
#pragma unroll
    for (int i = 0; i < 2; i++)
#pragma unroll
        for (int j = 0; j < 4; j++) acc[i][j] = (f32x4){0.f, 0.f, 0.f, 0.f};

    bf16x8 af[2][2], bfr[4][2];
    for (int t = 0; t < TAPS; ++t) {
        const int cur = t & 1, nxt = cur ^ 1;
#pragma unroll
        for (int m2 = 0; m2 < 2; m2++)
#pragma unroll
            for (int kk = 0; kk < 2; kk++) {
                int row_ = wid * 32 + m2 * 16 + fr;
                af[m2][kk] = *(const bf16x8*)(lac + cur * 16384 + row_ * 128 +
                                              ((kk * 64 + hk) ^ askew));
            }
#pragma unroll
        for (int n4 = 0; n4 < 4; n4++)
#pragma unroll
            for (int kk = 0; kk < 2; kk++) {
                int l_ = n4 * 16 + fr + t;   // jl + tap shift
                bfr[n4][kk] = *(const bf16x8*)(lxc + l_ * 128 +
                                  ((kk * 64 + hk) ^ ((l_ & 7) << 4)));
            }
        if (t + 1 < TAPS) STAGE_A9(t + 1, nxt)
        __builtin_amdgcn_s_setprio(1);
#pragma unroll
        for (int kk = 0; kk < 2; kk++)
#pragma unroll
            for (int m2 = 0; m2 < 2; m2++)
#pragma unroll
                for (int n4 = 0; n4 < 4; n4++)
                    acc[m2][n4] = __builtin_amdgcn_mfma_f32_16x16x32_bf16(
                        af[m2][kk], bfr[n4][kk], acc[m2][n4], 0, 0, 0);
        __builtin_amdgcn_s_setprio(0);
        __syncthreads();
    }

    // epilogue: C/D layout col=lane&15, row=(lane>>4)*4+j  [m89]
#pragma unroll
    for (int m2 = 0; m2 < 2; m2++) {
#pragma unroll
        for (int n4 = 0; n4 < 4; n4++) {
            int colk = jt * 64 + n4 * 16 + fr;
            int f0 = wid * 32 + m2 * 16 + ((lane >> 4) << 2);
#pragma unroll
            for (int j = 0; j < 4; j++) {
                int sig2 = n * 128 + f0 + j;
                Z[(size_t)sig2 * KD + colk] = f2bf(acc[m2][n4][j]);
            }
        }
    }
}

// ============ 256x256 MFMA GEMM, 2-barrier/K-tile, 16x16x32 grain ==========
// r15 delta: SINGLE staging point per tile — full tile t+2 (A+B, 8 gloads)
// issued after BAR#1 (both cur regions provably dead: lgkm(0)+BAR); counted
// vmcnt(8) = one full tile in flight. Ledger: entering tile t, tile t fully
// landed, tile t+1's 8 gloads outstanding. Tails: t=NT-2 -> vmcnt(0).
#define MFMA_Q(AS, BS, MH, NH)                                              \
    __builtin_amdgcn_s_setprio(1);                                          \
    _Pragma("unroll")                                                       \
    for (int kk = 0; kk < 2; kk++)                                          \
        _Pragma("unroll")                                                   \
        for (int m4 = 0; m4 < 4; m4++)                                      \
            _Pragma("unroll")                                               \
            for (int n2 = 0; n2 < 2; n2++)                                  \
                acc[(MH)*4 + m4][(NH)*2 + n2] =                             \
                    __builtin_amdgcn_mfma_f32_16x16x32_bf16(                \
                        AS[m4][kk], BS[n2][kk],                             \
                        acc[(MH)*4 + m4][(NH)*2 + n2], 0, 0, 0);            \
    __builtin_amdgcn_s_setprio(0);

#define LOAD_A(AS, MH, BUF)                                                 \
    _Pragma("unroll")                                                       \
    for (int m4 = 0; m4 < 4; m4++)                                          \
        _Pragma("unroll")                                                   \
        for (int kk = 0; kk < 2; kk++) {                                    \
            int row_ = wr * 128 + (MH)*64 + m4 * 16 + fr;                   \
            AS[m4][kk] = *(const bf16x8*)(smem + (BUF)*32768 +              \
                          row_ * 128 + ((kk * 64 + hk) ^ askew));           \
        }

#define LOAD_B(BS, NH, BUF)                                                 \
    _Pragma("unroll")                                                       \
    for (int n2 = 0; n2 < 2; n2++)                                          \
        _Pragma("unroll")                                                   \
        for (int kk = 0; kk < 2; kk++) {                                    \
            int row_ = wc * 64 + (NH)*32 + n2 * 16 + fr;                    \
            BS[n2][kk] = *(const bf16x8*)(smem + 65536 + (BUF)*32768 +      \
                          row_ * 128 + ((kk * 64 + hk) ^ askew));           \
        }

#define STAGE(Q, R, BUF)                                                    \
    {                                                                       \
        const u16* g_ = ((R) < 2) ? gA : gB;                                \
        size_t ro_ = (size_t)((R)&1) * 128 * K;                             \
        int lb_ = (((R) < 2) ? 0 : 65536) + (BUF)*32768 +                   \
                  (((R)&1) * 128 + wid * 16) * 128;                         \
        gload16(g_ + ro_ + (Q)*64, smem + lb_);                             \
        gload16(g_ + ro_ + (size_t)8 * K + (Q)*64, smem + lb_ + 1024);      \
    }

#define BAR() __builtin_amdgcn_s_barrier()

template <int MODE>
__global__ __launch_bounds__(512, 1) void gemm256(const u16* __restrict__ A,
                                                  const u16* __restrict__ B,
                                                  int K, int gridN,
                                                  void* __restrict__ Out,
                                                  int ldo,
                                                  const float* __restrict__ bias) {
    extern __shared__ char smem[];
    const int tid = threadIdx.x;
    const int lane = tid & 63, wid = tid >> 6;
    const int wr = wid >> 2, wc = wid & 3;
    const int fr = lane & 15;
    const int hk = (lane >> 4) << 4;
    const int askew = (fr & 7) << 4;

    const int nwg = (int)gridDim.x, cpx = nwg >> 3;
    const int bid = (int)blockIdx.x;
    const int wg = (bid & 7) * cpx + (bid >> 3);
    const int tm = wg / gridN, tn = wg % gridN;
    const int NT = K >> 6;

    f32x4 acc[8][4];
#pragma unroll
    for (int i = 0; i < 8; i++)
#pragma unroll
        for (int j = 0; j < 4; j++) acc[i][j] = (f32x4){0.f, 0.f, 0.f, 0.f};

    const int srow = lane >> 3;
    const int scol = ((lane & 7) ^ srow) * 8;
    const u16* gA = A + (size_t)(tm * 256 + wid * 16 + srow) * K + scol;
    const u16* gB = B + (size_t)(tn * 256 + wid * 16 + srow) * K + scol;

    // prologue: full tile0 -> buf0 (8), full tile1 -> buf1 (8);
    // vmcnt(8): tile0 landed, tile1 in flight.
    STAGE(0, 0, 0) STAGE(0, 1, 0) STAGE(0, 2, 0) STAGE(0, 3, 0)
    STAGE(1, 0, 1) STAGE(1, 1, 1) STAGE(1, 2, 1) STAGE(1, 3, 1)
    asm volatile("s_waitcnt vmcnt(8)" ::: "memory");
    BAR();

    bf16x8 a0[4][2], a1[4][2], b0[2][2], b1[2][2];
    for (int t = 0; t < NT; ++t) {
        const int cur = t & 1, nxt = cur ^ 1;
        LOAD_A(a0, 0, cur)
        LOAD_B(b0, 0, cur)
        LOAD_B(b1, 1, cur)
        MFMA_Q(a0, b0, 0, 0)
        LOAD_A(a1, 1, cur)          // issued under q00's MFMA shadow
        MFMA_Q(a0, b1, 0, 1)
        asm volatile("s_waitcnt lgkmcnt(0)" ::: "memory");  // cur reads done
        __builtin_amdgcn_sched_barrier(0);
        BAR();                       // #1: cur A+B regions dead block-wide
        if (t + 2 < NT) {            // stage FULL tile t+2 -> cur
            STAGE(t + 2, 0, cur) STAGE(t + 2, 1, cur)
            STAGE(t + 2, 2, cur) STAGE(t + 2, 3, cur)
        }
        MFMA_Q(a1, b1, 1, 1)
        MFMA_Q(a1, b0, 1, 0)
        if (t + 2 < NT) {
            asm volatile("s_waitcnt vmcnt(8)" ::: "memory");  // t+1 landed
        } else if (t + 1 < NT) {
            asm volatile("s_waitcnt vmcnt(0)" ::: "memory");  // drain for last
        }
        BAR();                       // #2: publish nxt
    }

    // epilogue: C/D frag layout col=lane&15, row=(lane>>4)*4+j  [m89]
#pragma unroll
    for (int m = 0; m < 8; m++) {
#pragma unroll
        for (int n = 0; n < 4; n++) {
            int col  = tn * 256 + wc * 64 + n * 16 + fr;
            int row0 = tm * 256 + wr * 128 + m * 16 + ((lane >> 4) << 2);
#pragma unroll
            for (int j = 0; j < 4; j++) {
                int grow = row0 + j;
                if (MODE == 0) {
                    ((u16*)Out)[(size_t)grow * ldo + col] = f2bf(acc[m][n][j]);
                } else {
                    if (col < OW) {
                        ((float*)Out)[(size_t)grow * OW + col] =
                            acc[m][n][j] + bias[grow & 127];
                    }
                }
            }
        }
    }
}

// ---------- launch ----------
extern "C" void kernel_launch(void* const* d_in, const int* in_sizes, int n_in,
                              void* d_out, int out_size, void* d_ws, size_t ws_size,
                              hipStream_t stream) {
    (void)in_sizes; (void)n_in; (void)out_size; (void)ws_size;
    const float* x    = (const float*)d_in[0];
    const float* filt = (const float*)d_in[1];
    const float* bias = (const float*)d_in[2];

    char* ws = (char*)d_ws;
    u16* XT = (u16*)(ws);                  // 32*4352*64*2 = 17,825,792 B
    u16* Z  = (u16*)(ws + 17825792);       // 4096*4160*2  = 34,078,720 B
    u16* Dt = (u16*)(ws + 51904512);       // 4096*4160*2  = 34,078,720 B
    u16* F2 = (u16*)(ws + 85983232);       // 128*576*2    = 147,456 B
    // total: 86,130,688 B

    hipFuncSetAttribute(reinterpret_cast<const void*>(gemm256<1>),
                        hipFuncAttributeMaxDynamicSharedMemorySize, 131072);

    prep_all<<<2176 + SIG2 + 288, 256, 0, stream>>>(x, XT, Dt, filt, F2);
    conv9<<<dim3(KD / 64, NB), 256, 0, stream>>>(XT, F2, Z);
    gemm256<1><<<16 * 16, 512, 131072, stream>>>(
        Z, Dt, KD, 16, d_out, OW, bias);
}

// Round 17
// 166.981 us; speedup vs baseline: 1.0201x; 1.0201x over previous
//
#include <hip/hip_runtime.h>
#include <hip/hip_bf16.h>

typedef unsigned short u16;
typedef unsigned int   u32;

using bf16x8 = __attribute__((ext_vector_type(8))) short;
using f32x4  = __attribute__((ext_vector_type(4))) float;

// ---------- constants ----------
#define NB    32      // batch
#define CC    64      // in channels
#define WW_   4096    // input width
#define FF    128     // out channels
#define TAPS  9
#define KBINS 3597    // half_compressed
#define N2    7194    // compress_fft_size
#define OW    4088    // out width
#define SIG2  4096    // N*F
#define JMAX  4104    // conv support: tau in [-8,4095], j = tau+8
#define KD    4160    // padded conv length (mult of 64)
#define XTROWS 4352   // 64 zero + 4096 data + 192 zero
#define PBIG  58933248   // 8192*7194 (< 2^31; 2*PBIG also < 2^31)

__device__ __forceinline__ u16 f2bf(float f) {
    u32 u = __float_as_uint(f);
    return (u16)((u + 0x7FFFu + ((u >> 16) & 1u)) >> 16);
}
// HW trig, input in REVOLUTIONS (ISA: D=sin(S0*2pi)), arg kept in [0,1)
__device__ __forceinline__ float vsin(float x) {
    float r; asm("v_sin_f32 %0, %1" : "=v"(r) : "v"(x)); return r;
}
__device__ __forceinline__ float vrcp(float x) {
    float r; asm("v_rcp_f32 %0, %1" : "=v"(r) : "v"(x)); return r;
}

// async global->LDS, 16B per lane; lds dest is wave-uniform base + lane*16
__device__ __forceinline__ void gload16(const void* g, void* l) {
    __builtin_amdgcn_global_load_lds(
        (const __attribute__((address_space(1))) void*)g,
        (__attribute__((address_space(3))) void*)l, 16, 0, 0);
}

// ---------- prep_all: cast_xt (blocks 0..2175) | gen_D (2176..6271) |
//                      F2 (6272..6559) — independent outputs, one launch ----
__global__ __launch_bounds__(256) void prep_all(const float* __restrict__ x,
                                                u16* __restrict__ XT,
                                                u16* __restrict__ D,
                                                const float* __restrict__ filt,
                                                u16* __restrict__ F2) {
    __shared__ u32 tl[64][33];          // cast branch only; [c][i2], +1 pad
    const int tid = threadIdx.x;
    const int b = blockIdx.x;

    if (b < 2176) {                     // ---- cast + transpose x -> XT ----
        const int it = b >> 5, n = b & 31;
        if (it >= 64) {                 // zero rows: R in [0,64) U [4160,4352)
            int zb = it - 64;           // 0..3
            int i2 = tid >> 3, cb = tid & 7;
            bf16x8 z;
#pragma unroll
            for (int q = 0; q < 8; q++) z[q] = 0;
#pragma unroll
            for (int e = 0; e < 2; e++) {
                int zr = zb * 64 + 2 * i2 + e;
                int R = (zr < 64) ? zr : (4096 + zr);
                *(bf16x8*)(XT + ((size_t)n * XTROWS + R) * 64 + cb * 8) = z;
            }
            return;
        }
        const int i0 = it * 64;
        {   // write side: c = tid>>2, 16 consecutive i packed 2/word
            int c = tid >> 2, iq = tid & 3;
            const float4* src = (const float4*)(x + ((size_t)n * CC + c) * WW_ +
                                                i0 + iq * 16);
#pragma unroll
            for (int q = 0; q < 4; q++) {
                float4 v = src[q];
                tl[c][iq * 8 + q * 2]     = (u32)f2bf(v.x) |
                                            ((u32)f2bf(v.y) << 16);
                tl[c][iq * 8 + q * 2 + 1] = (u32)f2bf(v.z) |
                                            ((u32)f2bf(v.w) << 16);
            }
        }
        __syncthreads();
        {   // read side: one u32 per channel gives BOTH rows of the i-pair
            int i2 = tid >> 3, cb = tid & 7;
            int R0 = i0 + 64 + 2 * i2, R1 = R0 + 1;
            bf16x8 vlo, vhi;
#pragma unroll
            for (int ci = 0; ci < 8; ci++) {
                u32 w = tl[cb * 8 + ci][i2];
                vlo[ci] = (short)(u16)(w & 0xffffu);
                vhi[ci] = (short)(u16)(w >> 16);
            }
            *(bf16x8*)(XT + ((size_t)n * XTROWS + R0) * 64 +
                       ((cb ^ (R0 & 7)) * 8)) = vlo;
            *(bf16x8*)(XT + ((size_t)n * XTROWS + R1) * 64 +
                       ((cb ^ (R1 & 7)) * 8)) = vhi;
        }
        return;
    }

    if (b < 2176 + SIG2) {              // ---- Dirichlet table D[t][j] ----
        // D = sin(7193*pi*a)/(N2*sin(pi*a)), a = (8192t - 7194(j-8))/P.
        // Division-free int32: |v| < P -> r = v(+P); 7193r mod 2P =
        // 7194*(r&16383) - r (+2P if <0), since 2P = 7194*16384.
        const int t = b - 2176;
        const int base = 8192 * t;
        u32* row = (u32*)(D + (size_t)t * KD);
        for (int p = tid; p < KD / 2; p += 256) {
            u32 pack = 0;
#pragma unroll
            for (int e = 0; e < 2; e++) {
                int j = 2 * p + e;
                float d = 0.f;
                if (j < JMAX) {
                    int v = base - 7194 * (j - 8);
                    int r = (v < 0) ? v + PBIG : v;
                    if (r == 0) {
                        d = 7193.0f / 7194.0f;
                    } else {
                        int m = 7194 * (r & 16383) - r;   // 7193r mod 2P
                        if (m < 0) m += 2 * PBIG;
                        float num = vsin((float)m *
                                         (float)(0.5 / (double)PBIG));
                        int rr = (r < PBIG - r) ? r : PBIG - r;
                        float den = (rr < (1 << 18))
                            ? (float)rr *
                              (float)(3.14159265358979323846 / (double)PBIG)
                            : vsin((float)r * (float)(0.5 / (double)PBIG));
                        d = num * vrcp(den) * (1.0f / 7194.0f);
                    }
                }
                pack |= (u32)f2bf(d) << (16 * e);
            }
            row[p] = pack;
        }
        return;
    }

    {                                   // ---- F2[f][w*64+c] ----
        int idx = (b - 2176 - SIG2) * 256 + tid;
        if (idx < FF * 576) {
            int f = idx / 576, wc = idx % 576;
            int w = wc >> 6, c = wc & 63;
            F2[idx] = f2bf(filt[((size_t)f * CC + c) * TAPS + w]);
        }
    }
}

// ============ conv9 (r13 v1, known-good): z[n*128+f][j] ====================
// A = F2 (128x576, dbuf per tap); B read DIRECT from staged x window
// (shift = tap), no Z materialization. Block (jt, n), 256 thr, 4 waves.
#define STAGE_A9(T, BUF)                                                    \
    _Pragma("unroll")                                                       \
    for (int q = 0; q < 4; q++) {                                           \
        gload16(F2 + (size_t)(wid * 32 + q * 8 + (lane >> 3)) * 576 +       \
                    (T) * 64 + (((lane & 7) ^ (lane >> 3)) * 8),            \
                lac + (BUF)*16384 + (wid * 32 + q * 8) * 128);              \
    }

__global__ __launch_bounds__(256, 2) void conv9(const u16* __restrict__ XT,
                                                const u16* __restrict__ F2,
                                                u16* __restrict__ Z) {
    __shared__ u16 la[2 * 128 * 64];   // 32 KB A dbuf
    __shared__ u16 lx[96 * 64];        // 12 KB x window (rows l, swz c-blk)
    const int tid = threadIdx.x;
    const int lane = tid & 63, wid = tid >> 6;
    const int jt = blockIdx.x, n = blockIdx.y;
    const int fr = lane & 15;
    const int hk = (lane >> 4) << 4;
    const int askew = (fr & 7) << 4;
    char* lac = (char*)la;
    char* lxc = (char*)lx;

    // stage x window: XT[n] rows jt*64+56 .. +151 (96 rows x 128B), linear.
    {
        const u16* src = XT + ((size_t)n * XTROWS + jt * 64 + 56) * 64;
#pragma unroll
        for (int q = 0; q < 3; q++) {
            int off = (wid * 3 + q) * 512;   // u16 units
            gload16(src + off + lane * 8, lxc + off * 2);
        }
    }
    STAGE_A9(0, 0)
    __syncthreads();

    f32x4 acc[2][4];
#pragma unroll
    for (int i = 0; i < 2; i++)
#pragma unroll
        for (int j = 0; j < 4; j++) acc[i][j] = (f32x4){0.f, 0.f, 0.f, 0.f};

    bf16x8 af[2][2], bfr[4][2];
    for (int t = 0; t < TAPS; ++t) {
        const int cur = t & 1, nxt = cur ^ 1;
#pragma unroll
        for (int m2 = 0; m2 < 2; m2++)
#pragma unroll
            for (int kk = 0; kk < 2; kk++) {
                int row_ = wid * 32 + m2 * 16 + fr;
                af[m2][kk] = *(const bf16x8*)(lac + cur * 16384 + row_ * 128 +
                                              ((kk * 64 + hk) ^ askew));
            }
#pragma unroll
        for (int n4 = 0; n4 < 4; n4++)
#pragma unroll
            for (int kk = 0; kk < 2; kk++) {
                int l_ = n4 * 16 + fr + t;   // jl + tap shift
                bfr[n4][kk] = *(const bf16x8*)(lxc + l_ * 128 +
                                  ((kk * 64 + hk) ^ ((l_ & 7) << 4)));
            }
        if (t + 1 < TAPS) STAGE_A9(t + 1, nxt)
        __builtin_amdgcn_s_setprio(1);
#pragma unroll
        for (int kk = 0; kk < 2; kk++)
#pragma unroll
            for (int m2 = 0; m2 < 2; m2++)
#pragma unroll
                for (int n4 = 0; n4 < 4; n4++)
                    acc[m2][n4] = __builtin_amdgcn_mfma_f32_16x16x32_bf16(
                        af[m2][kk], bfr[n4][kk], acc[m2][n4], 0, 0, 0);
        __builtin_amdgcn_s_setprio(0);
        __syncthreads();
    }

    // epilogue: C/D layout col=lane&15, row=(lane>>4)*4+j  [m89]
#pragma unroll
    for (int m2 = 0; m2 < 2; m2++) {
#pragma unroll
        for (int n4 = 0; n4 < 4; n4++) {
            int colk = jt * 64 + n4 * 16 + fr;
            int f0 = wid * 32 + m2 * 16 + ((lane >> 4) << 2);
#pragma unroll
            for (int j = 0; j < 4; j++) {
                int sig2 = n * 128 + f0 + j;
                Z[(size_t)sig2 * KD + colk] = f2bf(acc[m2][n4][j]);
            }
        }
    }
}

// ============ 256x256 MFMA GEMM, 2-barrier/K-tile, 16x16x32 grain ==========
// r15-exact schedule (REVERT of r16's fused staging; known-good 123us):
// per K-tile t (cur=t&1): LOAD a0,b0,b1 (cur); STAGE B(t+1)->nxt; q00;
// LOAD a1 (under q00 shadow); q01; lgkm(0); BAR#1; STAGE A(t+2)->cur
// (A region dead); q11; q10; vmcnt(4); BAR#2. Tails: t=NT-2 -> vmcnt(0).
#define MFMA_Q(AS, BS, MH, NH)                                              \
    __builtin_amdgcn_s_setprio(1);                                          \
    _Pragma("unroll")                                                       \
    for (int kk = 0; kk < 2; kk++)                                          \
        _Pragma("unroll")                                                   \
        for (int m4 = 0; m4 < 4; m4++)                                      \
            _Pragma("unroll")                                               \
            for (int n2 = 0; n2 < 2; n2++)                                  \
                acc[(MH)*4 + m4][(NH)*2 + n2] =                             \
                    __builtin_amdgcn_mfma_f32_16x16x32_bf16(                \
                        AS[m4][kk], BS[n2][kk],                             \
                        acc[(MH)*4 + m4][(NH)*2 + n2], 0, 0, 0);            \
    __builtin_amdgcn_s_setprio(0);

#define LOAD_A(AS, MH, BUF)                                                 \
    _Pragma("unroll")                                                       \
    for (int m4 = 0; m4 < 4; m4++)                                          \
        _Pragma("unroll")                                                   \
        for (int kk = 0; kk < 2; kk++) {                                    \
            int row_ = wr * 128 + (MH)*64 + m4 * 16 + fr;                   \
            AS[m4][kk] = *(const bf16x8*)(smem + (BUF)*32768 +              \
                          row_ * 128 + ((kk * 64 + hk) ^ askew));           \
        }

#define LOAD_B(BS, NH, BUF)                                                 \
    _Pragma("unroll")                                                       \
    for (int n2 = 0; n2 < 2; n2++)                                          \
        _Pragma("unroll")                                                   \
        for (int kk = 0; kk < 2; kk++) {                                    \
            int row_ = wc * 64 + (NH)*32 + n2 * 16 + fr;                    \
            BS[n2][kk] = *(const bf16x8*)(smem + 65536 + (BUF)*32768 +      \
                          row_ * 128 + ((kk * 64 + hk) ^ askew));           \
        }

#define STAGE(Q, R, BUF)                                                    \
    {                                                                       \
        const u16* g_ = ((R) < 2) ? gA : gB;                                \
        size_t ro_ = (size_t)((R)&1) * 128 * K;                             \
        int lb_ = (((R) < 2) ? 0 : 65536) + (BUF)*32768 +                   \
                  (((R)&1) * 128 + wid * 16) * 128;                         \
        gload16(g_ + ro_ + (Q)*64, smem + lb_);                             \
        gload16(g_ + ro_ + (size_t)8 * K + (Q)*64, smem + lb_ + 1024);      \
    }

#define BAR() __builtin_amdgcn_s_barrier()

template <int MODE>
__global__ __launch_bounds__(512, 1) void gemm256(const u16* __restrict__ A,
                                                  const u16* __restrict__ B,
                                                  int K, int gridN,
                                                  void* __restrict__ Out,
                                                  int ldo,
                                                  const float* __restrict__ bias) {
    extern __shared__ char smem[];
    const int tid = threadIdx.x;
    const int lane = tid & 63, wid = tid >> 6;
    const int wr = wid >> 2, wc = wid & 3;
    const int fr = lane & 15;
    const int hk = (lane >> 4) << 4;
    const int askew = (fr & 7) << 4;

    const int nwg = (int)gridDim.x, cpx = nwg >> 3;
    const int bid = (int)blockIdx.x;
    const int wg = (bid & 7) * cpx + (bid >> 3);
    const int tm = wg / gridN, tn = wg % gridN;
    const int NT = K >> 6;

    f32x4 acc[8][4];
#pragma unroll
    for (int i = 0; i < 8; i++)
#pragma unroll
        for (int j = 0; j < 4; j++) acc[i][j] = (f32x4){0.f, 0.f, 0.f, 0.f};

    const int srow = lane >> 3;
    const int scol = ((lane & 7) ^ srow) * 8;
    const u16* gA = A + (size_t)(tm * 256 + wid * 16 + srow) * K + scol;
    const u16* gB = B + (size_t)(tn * 256 + wid * 16 + srow) * K + scol;

    // prologue: full tile0 -> buf0, A(1) -> buf1; leaves A(1) in flight
    STAGE(0, 0, 0) STAGE(0, 1, 0) STAGE(0, 2, 0) STAGE(0, 3, 0)
    STAGE(1, 0, 1) STAGE(1, 1, 1)
    asm volatile("s_waitcnt vmcnt(4)" ::: "memory");
    BAR();

    bf16x8 a0[4][2], a1[4][2], b0[2][2], b1[2][2];
    for (int t = 0; t < NT; ++t) {
        const int cur = t & 1, nxt = cur ^ 1;
        LOAD_A(a0, 0, cur)
        LOAD_B(b0, 0, cur)
        LOAD_B(b1, 1, cur)
        if (t + 1 < NT) { STAGE(t + 1, 2, nxt) STAGE(t + 1, 3, nxt) }
        MFMA_Q(a0, b0, 0, 0)
        LOAD_A(a1, 1, cur)          // issued under q00's MFMA shadow
        MFMA_Q(a0, b1, 0, 1)
        asm volatile("s_waitcnt lgkmcnt(0)" ::: "memory");  // cur-A reads done
        __builtin_amdgcn_sched_barrier(0);
        BAR();                       // #1: cur-A region now dead block-wide
        if (t + 2 < NT) { STAGE(t + 2, 0, cur) STAGE(t + 2, 1, cur) }
        MFMA_Q(a1, b1, 1, 1)
        MFMA_Q(a1, b0, 1, 0)
        if (t + 2 < NT) {
            asm volatile("s_waitcnt vmcnt(4)" ::: "memory");  // A(t+1),B(t+1) in
        } else if (t + 1 < NT) {
            asm volatile("s_waitcnt vmcnt(0)" ::: "memory");  // drain for last
        }
        BAR();                       // #2: publish nxt
    }

    // epilogue: C/D frag layout col=lane&15, row=(lane>>4)*4+j  [m89]
#pragma unroll
    for (int m = 0; m < 8; m++) {
#pragma unroll
        for (int n = 0; n < 4; n++) {
            int col  = tn * 256 + wc * 64 + n * 16 + fr;
            int row0 = tm * 256 + wr * 128 + m * 16 + ((lane >> 4) << 2);
#pragma unroll
            for (int j = 0; j < 4; j++) {
                int grow = row0 + j;
                if (MODE == 0) {
                    ((u16*)Out)[(size_t)grow * ldo + col] = f2bf(acc[m][n][j]);
                } else {
                    if (col < OW) {
                        ((float*)Out)[(size_t)grow * OW + col] =
                            acc[m][n][j] + bias[grow & 127];
                    }
                }
            }
        }
    }
}

// ---------- launch ----------
extern "C" void kernel_launch(void* const* d_in, const int* in_sizes, int n_in,
                              void* d_out, int out_size, void* d_ws, size_t ws_size,
                              hipStream_t stream) {
    (void)in_sizes; (void)n_in; (void)out_size; (void)ws_size;
    const float* x    = (const float*)d_in[0];
    const float* filt = (const float*)d_in[1];
    const float* bias = (const float*)d_in[2];

    char* ws = (char*)d_ws;
    u16* XT = (u16*)(ws);                  // 32*4352*64*2 = 17,825,792 B
    u16* Z  = (u16*)(ws + 17825792);       // 4096*4160*2  = 34,078,720 B
    u16* Dt = (u16*)(ws + 51904512);       // 4096*4160*2  = 34,078,720 B
    u16* F2 = (u16*)(ws + 85983232);       // 128*576*2    = 147,456 B
    // total: 86,130,688 B

    hipFuncSetAttribute(reinterpret_cast<const void*>(gemm256<1>),
                        hipFuncAttributeMaxDynamicSharedMemorySize, 131072);

    prep_all<<<2176 + SIG2 + 288, 256, 0, stream>>>(x, XT, Dt, filt, F2);
    conv9<<<dim3(KD / 64, NB), 256, 0, stream>>>(XT, F2, Z);
    gemm256<1><<<16 * 16, 512, 131072, stream>>>(
        Z, Dt, KD, 16, d_out, OW, bias);
}